// Round 11
// baseline (238.858 us; speedup 1.0000x reference)
//
#include <hip/hip_runtime.h>
#include <hip/hip_bf16.h>
#include <cstddef>

// ---------------- problem constants ----------------
#define BB   8
#define CC   2
#define FF   256
#define TT   4160      // ncoefs
#define SS   64        // nb_slices
#define NW   128       // NWIN
#define KW   256       // 2*NWIN
#define EPSV 1e-5f

typedef __attribute__((ext_vector_type(8))) short bf16x8;   // 8 bf16 = 4 VGPRs
typedef __attribute__((ext_vector_type(4))) float f32x4;
typedef __attribute__((ext_vector_type(4))) unsigned int u32x4;

// ---------------- ws layout (float offsets) ----------------
#define YOFF    0
#define ZOFF    16777216
#define W1OFF   25427968
#define W2OFF   25444352
#define STATF   25462784
#define OFF_DA     256
#define OFF_DB     384
#define OFF_DIAB   544
#define OFF_STATR  1024    // 64 reps x [sum(128) | sq(128)]  (stage-1)
#define OFF_STATR2 17408   // 64 reps x [sum(16)  | sq(16) ]  (stage-2)
#define STAT_NZ 19456

// manual bf16 conversions (RNE) — cold paths only
__device__ __forceinline__ unsigned short f2bf(float f) {
    unsigned int u = __builtin_bit_cast(unsigned int, f);
    u = (u + 0x7FFFu + ((u >> 16) & 1u)) >> 16;
    return (unsigned short)u;
}
__device__ __forceinline__ float bf2f(unsigned short h) {
    return __builtin_bit_cast(float, (unsigned int)h << 16);
}
// packed f32x2 -> bf16x2 (RNE) via header intrinsic (lowers to v_cvt_pk_bf16_f32)
__device__ __forceinline__ unsigned int pk2bf(float lo, float hi) {
    float2 f; f.x = lo; f.y = hi;
    __hip_bfloat162 h = __float22bfloat162_rn(f);
    unsigned int r;
    __builtin_memcpy(&r, &h, 4);
    return r;
}

// ---------------- prep: zero stats + frag-ordered bf16 W_deo (w1) + W_di (w2) ----------------
__global__ __launch_bounds__(256) void k_prep(
    const float* __restrict__ Wdeo,
    const float* __restrict__ Wdi0, const float* __restrict__ Wdi1,
    const float* __restrict__ Wdi2, const float* __restrict__ Wdi3,
    const float* __restrict__ Wdi4,
    unsigned short* __restrict__ w1, unsigned short* __restrict__ w2,
    float* __restrict__ statz)
{
    int gid = blockIdx.x * 256 + threadIdx.x;
    if (gid < STAT_NZ) statz[gid] = 0.f;
    int id = gid - STAT_NZ;
    if (id >= 0 && id < 32768) {
        int j = id & 7, lane = (id >> 3) & 63, nt = (id >> 9) & 7, ks = id >> 12;
        int n = nt * 16 + (lane & 15);
        int k = ks * 32 + ((lane >> 4) << 3) + j;
        w1[id] = f2bf(Wdeo[n * KW + k]);
    }
    id -= 32768;
    if (id >= 0 && id < 36864) {
        const float* W; int base, Tk;
        if (id < 2048)       { W = Wdi0; base = 0;     Tk = 1; }
        else if (id < 6144)  { W = Wdi1; base = 2048;  Tk = 2; }
        else if (id < 12288) { W = Wdi2; base = 6144;  Tk = 3; }
        else if (id < 20480) { W = Wdi3; base = 12288; Tk = 4; }
        else                 { W = Wdi4; base = 20480; Tk = 8; }
        int e = id - base;
        int j = e & 7, lane = (e >> 3) & 63, rest = e >> 9;
        int t = rest % Tk, ks = rest / Tk;
        int n = t * 16 + (lane & 15);
        int k = ks * 32 + ((lane >> 4) << 3) + j;
        w2[id] = f2bf(W[n * NW + k]);
    }
}

// ---------------- stage 1: normalize + deoverlap MFMA + stats (1 row / block) ----------------
// STATIC 5-deep load phase (all 5 float4 loads in flight, one vmcnt drain) ->
// convert+ds_write phase. Pads (p4 outside [16,1056)) are written as ZERO
// (reference normalizes x first, THEN zero-pads). ks=0 w1 fragments are
// loaded BEFORE the barrier so their latency hides under the staging drain.
__global__ __launch_bounds__(256) void k_deoverlap(
    const float* __restrict__ x, const float* __restrict__ imean,
    const float* __restrict__ iscale, const unsigned short* __restrict__ w1,
    unsigned short* __restrict__ y, float* __restrict__ statR)
{
    __shared__ __align__(16) unsigned short xs[4288];
    __shared__ float psA[4][64], pqA[4][64];
    const int tid = threadIdx.x;
    const int r   = blockIdx.x;
    const int c   = (r >> 8) & 1;
    const int lane = tid & 63, wv = tid >> 6;
    const int q = lane >> 4, m = lane & 15;

    // ks=0 B-fragments: issue before staging so they're ready after the barrier
    bf16x8 Bc0 = *(const bf16x8*)(w1 + ((size_t)((2 * wv + 0) * 64 + lane) << 3));
    bf16x8 Bc1 = *(const bf16x8*)(w1 + ((size_t)((2 * wv + 1) * 64 + lane) << 3));

    {
        const float mval = imean[r & 255], sval = iscale[r & 255];
        const float* xr = x + (size_t)r * TT;
        // p4 = tid + k*256, k=0..4 (p4 < 1072). Valid x window: p4 in [16, 1056).
        float4 xv[5];
#pragma unroll
        for (int k = 0; k < 5; ++k) {
            int p4 = tid + k * 256;
            float4 v; v.x = 0.f; v.y = 0.f; v.z = 0.f; v.w = 0.f;
            if (p4 >= 16 && p4 < 1056)
                v = *(const float4*)&xr[p4 * 4 - 64];
            xv[k] = v;
        }
#pragma unroll
        for (int k = 0; k < 5; ++k) {
            int p4 = tid + k * 256;
            if (p4 < 1072) {
                int i = p4 * 4;
                int phys = i ^ (((i >> 6) & 7) << 3);   // 4-elem group contiguous under swizzle
                uint2 pk;
                if (p4 >= 16 && p4 < 1056) {
                    pk.x = pk2bf((xv[k].x + mval) * sval, (xv[k].y + mval) * sval);
                    pk.y = pk2bf((xv[k].z + mval) * sval, (xv[k].w + mval) * sval);
                } else {
                    pk.x = 0u; pk.y = 0u;               // zero-pad AFTER normalize semantics
                }
                *(uint2*)&xs[phys] = pk;
            }
        }
    }
    __syncthreads();

    f32x4 acc[4][2] = {};   // [stile][ntile]; D reg dim = n (contiguous in y)
#pragma unroll
    for (int ks = 0; ks < 8; ++ks) {
        bf16x8 Bn0, Bn1;
        if (ks < 7) {
            Bn0 = *(const bf16x8*)(w1 + ((size_t)(((ks + 1) * 8 + 2 * wv + 0) * 64 + lane) << 3));
            Bn1 = *(const bf16x8*)(w1 + ((size_t)(((ks + 1) * 8 + 2 * wv + 1) * 64 + lane) << 3));
        }
        const int k0 = ks * 32;
#pragma unroll
        for (int st = 0; st < 4; ++st) {
            int idx  = (st * 16 + m) * 64 + k0 + q * 8;
            int phys = idx ^ (((idx >> 6) & 7) << 3);
            bf16x8 A = *(const bf16x8*)&xs[phys];
            acc[st][0] = __builtin_amdgcn_mfma_f32_16x16x32_bf16(Bc0, A, acc[st][0], 0, 0, 0);
            acc[st][1] = __builtin_amdgcn_mfma_f32_16x16x32_bf16(Bc1, A, acc[st][1], 0, 0, 0);
        }
        Bc0 = Bn0; Bc1 = Bn1;
    }

    // y store: row s = st*16+m, cols n = (2wv+t)*16 + q*4 + reg -> one 8B store
#pragma unroll
    for (int st = 0; st < 4; ++st) {
        float ps = 0.f, pq = 0.f;
#pragma unroll
        for (int t = 0; t < 2; ++t) {
            uint2 u;
            u.x = pk2bf(acc[st][t][0], acc[st][t][1]);
            u.y = pk2bf(acc[st][t][2], acc[st][t][3]);
            *(uint2*)&y[(size_t)r * 8192 + (st * 16 + m) * NW + (2 * wv + t) * 16 + q * 4] = u;
#pragma unroll
            for (int reg = 0; reg < 4; ++reg) {
                float v = acc[st][t][reg];
                ps += v; pq += v * v;
            }
        }
        ps += __shfl_xor(ps, 16, 64);  pq += __shfl_xor(pq, 16, 64);
        ps += __shfl_xor(ps, 32, 64);  pq += __shfl_xor(pq, 32, 64);
        if (q == 0) { psA[wv][st * 16 + m] = ps; pqA[wv][st * 16 + m] = pq; }
    }
    __syncthreads();
    if (tid < 128) {
        int s = tid & 63, which = tid >> 6;
        float v = which ? (pqA[0][s] + pqA[1][s] + pqA[2][s] + pqA[3][s])
                        : (psA[0][s] + psA[1][s] + psA[2][s] + psA[3][s]);
        int rep = blockIdx.x & 63;
        atomicAdd(&statR[rep * 256 + which * 128 + c * SS + s], v);
    }
}

// ---------------- stage 1b: fold replicas -> per-(c,s) BN coefficients ----------------
__global__ void k_deo_ab(const float* __restrict__ statR,
                         const float* __restrict__ g, const float* __restrict__ be,
                         float* __restrict__ da, float* __restrict__ db)
{
    __shared__ float red[4][256];
    int tid = threadIdx.x;
    int i = tid & 127, h = tid >> 7;          // 512 threads: 4 rep-chunks
    float sm = 0.f, sq = 0.f;
    for (int rep = h; rep < 64; rep += 4) {
        sm += statR[rep * 256 + i];
        sq += statR[rep * 256 + 128 + i];
    }
    red[h][i] = sm; red[h][128 + i] = sq;
    __syncthreads();
    if (h == 0) {
        sm = red[0][i] + red[1][i] + red[2][i] + red[3][i];
        sq = red[0][128 + i] + red[1][128 + i] + red[2][128 + i] + red[3][128 + i];
        int c = i >> 6;
        const float N = (float)(BB * FF * NW);
        float mean = sm / N;
        float var  = sq / N - mean * mean;
        float a = g[c] * rsqrtf(var + EPSV);
        da[i] = a;
        db[i] = be[c] - mean * a;
    }
}

// ---------------- stage 2 body: fused BN+ReLU + GEMM for one bucket sub-block ----------------
// v2: ALL 4*G y-fragment loads hoisted to block top (issued back-to-back,
// 4-8 in flight), BN transform done in bulk (overlaps tail latency), then a
// pure B-load + MFMA ks loop. Was: one y-load outstanding per wave.
template <int Tk, int G>
__device__ __forceinline__ void deinterp_body(
    int sub,
    const unsigned short* __restrict__ y, const unsigned short* __restrict__ wb,
    const float* __restrict__ da, const float* __restrict__ db,
    unsigned short* __restrict__ zz, float* __restrict__ statR2,
    int p, int freqs, int kidx, float* ssum, float* ssq)
{
    constexpr int MT = Tk * 16;
    const int tid = threadIdx.x, lane = tid & 63, wv = tid >> 6;
    const int q = lane >> 4, m = lane & 15;
    const int bc = sub & 15;
    const int fg = sub >> 4;
    const int c  = bc & 1;
    const int s  = wv * 16 + m;
    const float aS = da[c * SS + s], bS = db[c * SS + s];

    const unsigned short* ybase = y + ((size_t)(bc * FF + p + fg * G) * SS) * NW;

    // hoisted y loads: all issued before any use
    bf16x8 ar[G][4];
#pragma unroll
    for (int g = 0; g < G; ++g)
#pragma unroll
        for (int ks = 0; ks < 4; ++ks)
            ar[g][ks] = *(const bf16x8*)(ybase + ((size_t)g * SS + s) * NW + ks * 32 + q * 8);

    // bulk BN+ReLU -> bf16 A-fragments
    bf16x8 af[G][4];
#pragma unroll
    for (int g = 0; g < G; ++g)
#pragma unroll
        for (int ks = 0; ks < 4; ++ks) {
            u32x4 tp;
#pragma unroll
            for (int jj = 0; jj < 4; ++jj) {
                float f0 = fmaxf(fmaf(bf2f((unsigned short)ar[g][ks][2 * jj]),     aS, bS), 0.f);
                float f1 = fmaxf(fmaf(bf2f((unsigned short)ar[g][ks][2 * jj + 1]), aS, bS), 0.f);
                tp[jj] = pk2bf(f0, f1);
            }
            __builtin_memcpy(&af[g][ks], &tp, 16);
        }

    f32x4 acc[G][Tk] = {};
#pragma unroll
    for (int ks = 0; ks < 4; ++ks) {
        bf16x8 B[Tk];
#pragma unroll
        for (int t = 0; t < Tk; ++t)
            B[t] = *(const bf16x8*)(wb + ((size_t)((ks * Tk + t) * 64 + lane) << 3));
#pragma unroll
        for (int g = 0; g < G; ++g)
#pragma unroll
            for (int t = 0; t < Tk; ++t)
                acc[g][t] = __builtin_amdgcn_mfma_f32_16x16x32_bf16(B[t], af[g][ks], acc[g][t], 0, 0, 0);
    }

    float ls = 0.f, lq = 0.f;
#pragma unroll
    for (int g = 0; g < G; ++g) {
        size_t zrow = ((size_t)(bc * freqs + fg * G + g) * SS + wv * 16 + m) * MT;
#pragma unroll
        for (int t = 0; t < Tk; ++t) {
            uint2 u;
            u.x = pk2bf(acc[g][t][0], acc[g][t][1]);
            u.y = pk2bf(acc[g][t][2], acc[g][t][3]);
            *(uint2*)&zz[zrow + t * 16 + q * 4] = u;
#pragma unroll
            for (int reg = 0; reg < 4; ++reg) {
                float v = acc[g][t][reg];
                ls += v; lq += v * v;
            }
        }
    }
#pragma unroll
    for (int o = 32; o > 0; o >>= 1) {
        ls += __shfl_down(ls, o, 64);
        lq += __shfl_down(lq, o, 64);
    }
    if (lane == 0) { ssum[wv] = ls; ssq[wv] = lq; }
    __syncthreads();
    if (tid == 0) {
        int rep = sub & 63;
        atomicAdd(&statR2[rep * 32 + kidx * 2 + c],      ssum[0] + ssum[1] + ssum[2] + ssum[3]);
        atomicAdd(&statR2[rep * 32 + 16 + kidx * 2 + c], ssq[0] + ssq[1] + ssq[2] + ssq[3]);
    }
}

// ---------------- stage 2 fused: all 5 buckets in one launch (G halved for 2x TLP) ----------------
//   [    0,  512) -> bucket3 Tk=4 G=2  (512 blocks)
//   [  512, 1024) -> bucket2 Tk=3 G=2  (512 blocks)
//   [ 1024, 2048) -> bucket4 Tk=8 G=1  (1024 blocks)
//   [ 2048, 2304) -> bucket1 Tk=2 G=2  (256 blocks)
//   [ 2304, 2560) -> bucket0 Tk=1 G=2  (256 blocks)
__global__ __launch_bounds__(256) void k_deinterp_all(
    const unsigned short* __restrict__ y, const unsigned short* __restrict__ w2,
    const float* __restrict__ da, const float* __restrict__ db,
    unsigned short* __restrict__ z, float* __restrict__ statR2)
{
    __shared__ float ssum[4], ssq[4];
    const int b = blockIdx.x;
    if (b < 512) {
        deinterp_body<4, 2>(b,        y, w2 + 12288, da, db, z + 4718592, statR2, 128, 64, 3, ssum, ssq);
    } else if (b < 1024) {
        deinterp_body<3, 2>(b - 512,  y, w2 + 6144,  da, db, z + 1572864, statR2,  64, 64, 2, ssum, ssq);
    } else if (b < 2048) {
        deinterp_body<8, 1>(b - 1024, y, w2 + 20480, da, db, z + 8912896, statR2, 192, 64, 4, ssum, ssq);
    } else if (b < 2304) {
        deinterp_body<2, 2>(b - 2048, y, w2 + 2048,  da, db, z + 524288,  statR2,  32, 32, 1, ssum, ssq);
    } else {
        deinterp_body<1, 2>(b - 2304, y, w2 + 0,     da, db, z + 0,       statR2,   0, 32, 0, ssum, ssq);
    }
}

// ---------------- stage 2b: fold replicas -> per-(bucket,c) BN coefficients ----------------
__global__ void k_di_ab(const float* __restrict__ statR2,
                        const float* __restrict__ g0, const float* __restrict__ g1,
                        const float* __restrict__ g2, const float* __restrict__ g3,
                        const float* __restrict__ g4,
                        const float* __restrict__ b0, const float* __restrict__ b1,
                        const float* __restrict__ b2, const float* __restrict__ b3,
                        const float* __restrict__ b4,
                        float* __restrict__ ab)
{
    int tid = threadIdx.x;
    int i = tid >> 4, j = tid & 15;           // 160 threads: 16 lanes per output
    if (i < 10) {
        float sm = 0.f, sq = 0.f;
        for (int rep = j; rep < 64; rep += 16) {
            sm += statR2[rep * 32 + i];
            sq += statR2[rep * 32 + 16 + i];
        }
#pragma unroll
        for (int o = 8; o > 0; o >>= 1) {
            sm += __shfl_down(sm, o, 16);
            sq += __shfl_down(sq, o, 16);
        }
        if (j == 0) {
            int kb = i >> 1, c = i & 1;
            const float Nv[5] = {262144.f, 524288.f, 1572864.f, 2097152.f, 4194304.f};
            const float* gp[5] = {g0, g1, g2, g3, g4};
            const float* bp[5] = {b0, b1, b2, b3, b4};
            float mean = sm / Nv[kb];
            float var  = sq / Nv[kb] - mean * mean;
            float a = gp[kb][c] * rsqrtf(var + EPSV);
            ab[i * 2]     = a;
            ab[i * 2 + 1] = bp[kb][c] - mean * a;
        }
    }
}

// ---------------- BN+ReLU epilogue: bf16 z -> fp32 out (16 elems / thread) ----------------
// v2: two 16B z-loads issued together (2 in flight), 4x16B stores; grid halved.
__global__ __launch_bounds__(256) void k_bn_out(
    const unsigned short* __restrict__ z, const float* __restrict__ ab,
    float* __restrict__ out)
{
    int i16 = blockIdx.x * 256 + threadIdx.x;
    if (i16 >= 1081344) return;
    int kb, off16, cs16;
    if (i16 < 32768)       { kb = 0; off16 = 0;      cs16 = 2048;  }
    else if (i16 < 98304)  { kb = 1; off16 = 32768;  cs16 = 4096;  }
    else if (i16 < 294912) { kb = 2; off16 = 98304;  cs16 = 12288; }
    else if (i16 < 557056) { kb = 3; off16 = 294912; cs16 = 16384; }
    else                   { kb = 4; off16 = 557056; cs16 = 32768; }
    int c = ((i16 - off16) / cs16) & 1;
    float a = ab[(kb * 2 + c) * 2], b = ab[(kb * 2 + c) * 2 + 1];

    const unsigned short* zp = z + (size_t)i16 * 16;
    u32x4 w0 = *(const u32x4*)zp;          // 8 bf16
    u32x4 w1 = *(const u32x4*)(zp + 8);    // 8 bf16
    float* op = out + (size_t)i16 * 16;
#pragma unroll
    for (int h = 0; h < 2; ++h) {
        u32x4 w = h ? w1 : w0;
        float4 oA, oB;
        oA.x = fmaxf(fmaf(bf2f((unsigned short)(w[0] & 0xffffu)), a, b), 0.f);
        oA.y = fmaxf(fmaf(bf2f((unsigned short)(w[0] >> 16)),     a, b), 0.f);
        oA.z = fmaxf(fmaf(bf2f((unsigned short)(w[1] & 0xffffu)), a, b), 0.f);
        oA.w = fmaxf(fmaf(bf2f((unsigned short)(w[1] >> 16)),     a, b), 0.f);
        oB.x = fmaxf(fmaf(bf2f((unsigned short)(w[2] & 0xffffu)), a, b), 0.f);
        oB.y = fmaxf(fmaf(bf2f((unsigned short)(w[2] >> 16)),     a, b), 0.f);
        oB.z = fmaxf(fmaf(bf2f((unsigned short)(w[3] & 0xffffu)), a, b), 0.f);
        oB.w = fmaxf(fmaf(bf2f((unsigned short)(w[3] >> 16)),     a, b), 0.f);
        *(float4*)(op + h * 8)     = oA;
        *(float4*)(op + h * 8 + 4) = oB;
    }
}

// ---------------- launch ----------------
extern "C" void kernel_launch(void* const* d_in, const int* in_sizes, int n_in,
                              void* d_out, int out_size, void* d_ws, size_t ws_size,
                              hipStream_t stream)
{
    const float* x      = (const float*)d_in[0];
    const float* imean  = (const float*)d_in[1];
    const float* iscale = (const float*)d_in[2];
    const float* Wdeo   = (const float*)d_in[3];
    const float* gdeo   = (const float*)d_in[4];
    const float* bdeo   = (const float*)d_in[5];
    const float* Wdi[5] = {(const float*)d_in[7],  (const float*)d_in[10],
                           (const float*)d_in[13], (const float*)d_in[16],
                           (const float*)d_in[19]};
    const float* gdi[5] = {(const float*)d_in[8],  (const float*)d_in[11],
                           (const float*)d_in[14], (const float*)d_in[17],
                           (const float*)d_in[20]};
    const float* bdi[5] = {(const float*)d_in[9],  (const float*)d_in[12],
                           (const float*)d_in[15], (const float*)d_in[18],
                           (const float*)d_in[21]};
    float* out = (float*)d_out;
    float* ws  = (float*)d_ws;

    unsigned short* y  = (unsigned short*)(ws + YOFF);
    unsigned short* z  = (unsigned short*)(ws + ZOFF);
    unsigned short* w1 = (unsigned short*)(ws + W1OFF);
    unsigned short* w2 = (unsigned short*)(ws + W2OFF);
    float* st     = ws + STATF;
    float* da     = st + OFF_DA;
    float* db     = st + OFF_DB;
    float* diab   = st + OFF_DIAB;
    float* statR  = st + OFF_STATR;
    float* statR2 = st + OFF_STATR2;

    k_prep<<<348, 256, 0, stream>>>(Wdeo, Wdi[0], Wdi[1], Wdi[2], Wdi[3], Wdi[4],
                                    w1, w2, st);

    k_deoverlap<<<BB * CC * FF, 256, 0, stream>>>(x, imean, iscale, w1, y, statR);
    k_deo_ab<<<1, 512, 0, stream>>>(statR, gdeo, bdeo, da, db);

    k_deinterp_all<<<2560, 256, 0, stream>>>(y, w2, da, db, z, statR2);

    k_di_ab<<<1, 160, 0, stream>>>(statR2,
                                   gdi[0], gdi[1], gdi[2], gdi[3], gdi[4],
                                   bdi[0], bdi[1], bdi[2], bdi[3], bdi[4], diab);

    k_bn_out<<<4224, 256, 0, stream>>>(z, diab, out);
}

// Round 12
// 237.889 us; speedup vs baseline: 1.0041x; 1.0041x over previous
//
#include <hip/hip_runtime.h>
#include <hip/hip_bf16.h>
#include <cstddef>

// ---------------- problem constants ----------------
#define BB   8
#define CC   2
#define FF   256
#define TT   4160      // ncoefs
#define SS   64        // nb_slices
#define NW   128       // NWIN
#define KW   256       // 2*NWIN
#define EPSV 1e-5f

typedef __attribute__((ext_vector_type(8))) short bf16x8;   // 8 bf16 = 4 VGPRs
typedef __attribute__((ext_vector_type(4))) float f32x4;
typedef __attribute__((ext_vector_type(4))) unsigned int u32x4;

// ---------------- ws layout (float offsets) ----------------
#define YOFF    0
#define ZOFF    16777216
#define W1OFF   25427968
#define W2OFF   25444352
#define STATF   25462784
#define OFF_DA     256
#define OFF_DB     384
#define OFF_DIAB   544
#define OFF_STATR  1024    // 64 reps x [sum(128) | sq(128)]  (stage-1)
#define OFF_STATR2 17408   // 64 reps x [sum(16)  | sq(16) ]  (stage-2)
#define STAT_NZ 19456

// manual bf16 conversions (RNE) — cold paths only
__device__ __forceinline__ unsigned short f2bf(float f) {
    unsigned int u = __builtin_bit_cast(unsigned int, f);
    u = (u + 0x7FFFu + ((u >> 16) & 1u)) >> 16;
    return (unsigned short)u;
}
__device__ __forceinline__ float bf2f(unsigned short h) {
    return __builtin_bit_cast(float, (unsigned int)h << 16);
}
// packed f32x2 -> bf16x2 (RNE) via header intrinsic (lowers to v_cvt_pk_bf16_f32)
__device__ __forceinline__ unsigned int pk2bf(float lo, float hi) {
    float2 f; f.x = lo; f.y = hi;
    __hip_bfloat162 h = __float22bfloat162_rn(f);
    unsigned int r;
    __builtin_memcpy(&r, &h, 4);
    return r;
}

// ---------------- prep: zero stats + frag-ordered bf16 W_deo (w1) + W_di (w2) ----------------
__global__ __launch_bounds__(256) void k_prep(
    const float* __restrict__ Wdeo,
    const float* __restrict__ Wdi0, const float* __restrict__ Wdi1,
    const float* __restrict__ Wdi2, const float* __restrict__ Wdi3,
    const float* __restrict__ Wdi4,
    unsigned short* __restrict__ w1, unsigned short* __restrict__ w2,
    float* __restrict__ statz)
{
    int gid = blockIdx.x * 256 + threadIdx.x;
    if (gid < STAT_NZ) statz[gid] = 0.f;
    int id = gid - STAT_NZ;
    if (id >= 0 && id < 32768) {
        int j = id & 7, lane = (id >> 3) & 63, nt = (id >> 9) & 7, ks = id >> 12;
        int n = nt * 16 + (lane & 15);
        int k = ks * 32 + ((lane >> 4) << 3) + j;
        w1[id] = f2bf(Wdeo[n * KW + k]);
    }
    id -= 32768;
    if (id >= 0 && id < 36864) {
        const float* W; int base, Tk;
        if (id < 2048)       { W = Wdi0; base = 0;     Tk = 1; }
        else if (id < 6144)  { W = Wdi1; base = 2048;  Tk = 2; }
        else if (id < 12288) { W = Wdi2; base = 6144;  Tk = 3; }
        else if (id < 20480) { W = Wdi3; base = 12288; Tk = 4; }
        else                 { W = Wdi4; base = 20480; Tk = 8; }
        int e = id - base;
        int j = e & 7, lane = (e >> 3) & 63, rest = e >> 9;
        int t = rest % Tk, ks = rest / Tk;
        int n = t * 16 + (lane & 15);
        int k = ks * 32 + ((lane >> 4) << 3) + j;
        w2[id] = f2bf(W[n * NW + k]);
    }
}

// ---------------- stage 1: normalize + deoverlap MFMA + stats (1 row / block) ----------------
// STATIC 5-deep load phase (all 5 float4 loads in flight, one vmcnt drain) ->
// convert+ds_write phase. Pads (p4 outside [16,1056)) are written as ZERO
// (reference normalizes x first, THEN zero-pads). ks=0 w1 fragments are
// loaded BEFORE the barrier so their latency hides under the staging drain.
__global__ __launch_bounds__(256) void k_deoverlap(
    const float* __restrict__ x, const float* __restrict__ imean,
    const float* __restrict__ iscale, const unsigned short* __restrict__ w1,
    unsigned short* __restrict__ y, float* __restrict__ statR)
{
    __shared__ __align__(16) unsigned short xs[4288];
    __shared__ float psA[4][64], pqA[4][64];
    const int tid = threadIdx.x;
    const int r   = blockIdx.x;
    const int c   = (r >> 8) & 1;
    const int lane = tid & 63, wv = tid >> 6;
    const int q = lane >> 4, m = lane & 15;

    // ks=0 B-fragments: issue before staging so they're ready after the barrier
    bf16x8 Bc0 = *(const bf16x8*)(w1 + ((size_t)((2 * wv + 0) * 64 + lane) << 3));
    bf16x8 Bc1 = *(const bf16x8*)(w1 + ((size_t)((2 * wv + 1) * 64 + lane) << 3));

    {
        const float mval = imean[r & 255], sval = iscale[r & 255];
        const float* xr = x + (size_t)r * TT;
        // p4 = tid + k*256, k=0..4 (p4 < 1072). Valid x window: p4 in [16, 1056).
        float4 xv[5];
#pragma unroll
        for (int k = 0; k < 5; ++k) {
            int p4 = tid + k * 256;
            float4 v; v.x = 0.f; v.y = 0.f; v.z = 0.f; v.w = 0.f;
            if (p4 >= 16 && p4 < 1056)
                v = *(const float4*)&xr[p4 * 4 - 64];
            xv[k] = v;
        }
#pragma unroll
        for (int k = 0; k < 5; ++k) {
            int p4 = tid + k * 256;
            if (p4 < 1072) {
                int i = p4 * 4;
                int phys = i ^ (((i >> 6) & 7) << 3);   // 4-elem group contiguous under swizzle
                uint2 pk;
                if (p4 >= 16 && p4 < 1056) {
                    pk.x = pk2bf((xv[k].x + mval) * sval, (xv[k].y + mval) * sval);
                    pk.y = pk2bf((xv[k].z + mval) * sval, (xv[k].w + mval) * sval);
                } else {
                    pk.x = 0u; pk.y = 0u;               // zero-pad AFTER normalize semantics
                }
                *(uint2*)&xs[phys] = pk;
            }
        }
    }
    __syncthreads();

    f32x4 acc[4][2] = {};   // [stile][ntile]; D reg dim = n (contiguous in y)
#pragma unroll
    for (int ks = 0; ks < 8; ++ks) {
        bf16x8 Bn0, Bn1;
        if (ks < 7) {
            Bn0 = *(const bf16x8*)(w1 + ((size_t)(((ks + 1) * 8 + 2 * wv + 0) * 64 + lane) << 3));
            Bn1 = *(const bf16x8*)(w1 + ((size_t)(((ks + 1) * 8 + 2 * wv + 1) * 64 + lane) << 3));
        }
        const int k0 = ks * 32;
#pragma unroll
        for (int st = 0; st < 4; ++st) {
            int idx  = (st * 16 + m) * 64 + k0 + q * 8;
            int phys = idx ^ (((idx >> 6) & 7) << 3);
            bf16x8 A = *(const bf16x8*)&xs[phys];
            acc[st][0] = __builtin_amdgcn_mfma_f32_16x16x32_bf16(Bc0, A, acc[st][0], 0, 0, 0);
            acc[st][1] = __builtin_amdgcn_mfma_f32_16x16x32_bf16(Bc1, A, acc[st][1], 0, 0, 0);
        }
        Bc0 = Bn0; Bc1 = Bn1;
    }

    // y store: row s = st*16+m, cols n = (2wv+t)*16 + q*4 + reg -> one 8B store
#pragma unroll
    for (int st = 0; st < 4; ++st) {
        float ps = 0.f, pq = 0.f;
#pragma unroll
        for (int t = 0; t < 2; ++t) {
            uint2 u;
            u.x = pk2bf(acc[st][t][0], acc[st][t][1]);
            u.y = pk2bf(acc[st][t][2], acc[st][t][3]);
            *(uint2*)&y[(size_t)r * 8192 + (st * 16 + m) * NW + (2 * wv + t) * 16 + q * 4] = u;
#pragma unroll
            for (int reg = 0; reg < 4; ++reg) {
                float v = acc[st][t][reg];
                ps += v; pq += v * v;
            }
        }
        ps += __shfl_xor(ps, 16, 64);  pq += __shfl_xor(pq, 16, 64);
        ps += __shfl_xor(ps, 32, 64);  pq += __shfl_xor(pq, 32, 64);
        if (q == 0) { psA[wv][st * 16 + m] = ps; pqA[wv][st * 16 + m] = pq; }
    }
    __syncthreads();
    if (tid < 128) {
        int s = tid & 63, which = tid >> 6;
        float v = which ? (pqA[0][s] + pqA[1][s] + pqA[2][s] + pqA[3][s])
                        : (psA[0][s] + psA[1][s] + psA[2][s] + psA[3][s]);
        int rep = blockIdx.x & 63;
        atomicAdd(&statR[rep * 256 + which * 128 + c * SS + s], v);
    }
}

// ---------------- stage 1b: fold replicas -> per-(c,s) BN coefficients ----------------
__global__ void k_deo_ab(const float* __restrict__ statR,
                         const float* __restrict__ g, const float* __restrict__ be,
                         float* __restrict__ da, float* __restrict__ db)
{
    __shared__ float red[4][256];
    int tid = threadIdx.x;
    int i = tid & 127, h = tid >> 7;          // 512 threads: 4 rep-chunks
    float sm = 0.f, sq = 0.f;
    for (int rep = h; rep < 64; rep += 4) {
        sm += statR[rep * 256 + i];
        sq += statR[rep * 256 + 128 + i];
    }
    red[h][i] = sm; red[h][128 + i] = sq;
    __syncthreads();
    if (h == 0) {
        sm = red[0][i] + red[1][i] + red[2][i] + red[3][i];
        sq = red[0][128 + i] + red[1][128 + i] + red[2][128 + i] + red[3][128 + i];
        int c = i >> 6;
        const float N = (float)(BB * FF * NW);
        float mean = sm / N;
        float var  = sq / N - mean * mean;
        float a = g[c] * rsqrtf(var + EPSV);
        da[i] = a;
        db[i] = be[c] - mean * a;
    }
}

// ---------------- stage 2 body: fused BN+ReLU + GEMM for one bucket sub-block ----------------
// r10 interleaved form (one ar live at a time, low VGPR): r11's full hoist
// (+64 VGPR) dropped occupancy and regressed — TLP was already hiding latency.
template <int Tk, int G>
__device__ __forceinline__ void deinterp_body(
    int sub,
    const unsigned short* __restrict__ y, const unsigned short* __restrict__ wb,
    const float* __restrict__ da, const float* __restrict__ db,
    unsigned short* __restrict__ zz, float* __restrict__ statR2,
    int p, int freqs, int kidx, float* ssum, float* ssq)
{
    constexpr int MT = Tk * 16;
    const int tid = threadIdx.x, lane = tid & 63, wv = tid >> 6;
    const int q = lane >> 4, m = lane & 15;
    const int bc = sub & 15;
    const int fg = sub >> 4;
    const int c  = bc & 1;
    const int s  = wv * 16 + m;
    const float aS = da[c * SS + s], bS = db[c * SS + s];

    f32x4 acc[G][Tk] = {};
    const unsigned short* ybase = y + ((size_t)(bc * FF + p + fg * G) * SS) * NW;

#pragma unroll
    for (int ks = 0; ks < 4; ++ks) {
        bf16x8 B[Tk];
#pragma unroll
        for (int t = 0; t < Tk; ++t)
            B[t] = *(const bf16x8*)(wb + ((size_t)((ks * Tk + t) * 64 + lane) << 3));
#pragma unroll
        for (int g = 0; g < G; ++g) {
            bf16x8 ar = *(const bf16x8*)(ybase + ((size_t)g * SS + s) * NW + ks * 32 + q * 8);
            u32x4 tp;
#pragma unroll
            for (int jj = 0; jj < 4; ++jj) {
                float f0 = fmaxf(fmaf(bf2f((unsigned short)ar[2 * jj]),     aS, bS), 0.f);
                float f1 = fmaxf(fmaf(bf2f((unsigned short)ar[2 * jj + 1]), aS, bS), 0.f);
                tp[jj] = pk2bf(f0, f1);
            }
            bf16x8 af;
            __builtin_memcpy(&af, &tp, 16);
#pragma unroll
            for (int t = 0; t < Tk; ++t)
                acc[g][t] = __builtin_amdgcn_mfma_f32_16x16x32_bf16(B[t], af, acc[g][t], 0, 0, 0);
        }
    }

    float ls = 0.f, lq = 0.f;
#pragma unroll
    for (int g = 0; g < G; ++g) {
        size_t zrow = ((size_t)(bc * freqs + fg * G + g) * SS + wv * 16 + m) * MT;
#pragma unroll
        for (int t = 0; t < Tk; ++t) {
            uint2 u;
            u.x = pk2bf(acc[g][t][0], acc[g][t][1]);
            u.y = pk2bf(acc[g][t][2], acc[g][t][3]);
            *(uint2*)&zz[zrow + t * 16 + q * 4] = u;
#pragma unroll
            for (int reg = 0; reg < 4; ++reg) {
                float v = acc[g][t][reg];
                ls += v; lq += v * v;
            }
        }
    }
#pragma unroll
    for (int o = 32; o > 0; o >>= 1) {
        ls += __shfl_down(ls, o, 64);
        lq += __shfl_down(lq, o, 64);
    }
    if (lane == 0) { ssum[wv] = ls; ssq[wv] = lq; }
    __syncthreads();
    if (tid == 0) {
        int rep = sub & 63;
        atomicAdd(&statR2[rep * 32 + kidx * 2 + c],      ssum[0] + ssum[1] + ssum[2] + ssum[3]);
        atomicAdd(&statR2[rep * 32 + 16 + kidx * 2 + c], ssq[0] + ssq[1] + ssq[2] + ssq[3]);
    }
}

// ---------------- stage 2 fused: all 5 buckets in one launch (G halved for 2x TLP) ----------------
//   [    0,  512) -> bucket3 Tk=4 G=2  (512 blocks)
//   [  512, 1024) -> bucket2 Tk=3 G=2  (512 blocks)
//   [ 1024, 2048) -> bucket4 Tk=8 G=1  (1024 blocks)
//   [ 2048, 2304) -> bucket1 Tk=2 G=2  (256 blocks)
//   [ 2304, 2560) -> bucket0 Tk=1 G=2  (256 blocks)
__global__ __launch_bounds__(256) void k_deinterp_all(
    const unsigned short* __restrict__ y, const unsigned short* __restrict__ w2,
    const float* __restrict__ da, const float* __restrict__ db,
    unsigned short* __restrict__ z, float* __restrict__ statR2)
{
    __shared__ float ssum[4], ssq[4];
    const int b = blockIdx.x;
    if (b < 512) {
        deinterp_body<4, 2>(b,        y, w2 + 12288, da, db, z + 4718592, statR2, 128, 64, 3, ssum, ssq);
    } else if (b < 1024) {
        deinterp_body<3, 2>(b - 512,  y, w2 + 6144,  da, db, z + 1572864, statR2,  64, 64, 2, ssum, ssq);
    } else if (b < 2048) {
        deinterp_body<8, 1>(b - 1024, y, w2 + 20480, da, db, z + 8912896, statR2, 192, 64, 4, ssum, ssq);
    } else if (b < 2304) {
        deinterp_body<2, 2>(b - 2048, y, w2 + 2048,  da, db, z + 524288,  statR2,  32, 32, 1, ssum, ssq);
    } else {
        deinterp_body<1, 2>(b - 2304, y, w2 + 0,     da, db, z + 0,       statR2,   0, 32, 0, ssum, ssq);
    }
}

// ---------------- stage 2b: fold replicas -> per-(bucket,c) BN coefficients ----------------
__global__ void k_di_ab(const float* __restrict__ statR2,
                        const float* __restrict__ g0, const float* __restrict__ g1,
                        const float* __restrict__ g2, const float* __restrict__ g3,
                        const float* __restrict__ g4,
                        const float* __restrict__ b0, const float* __restrict__ b1,
                        const float* __restrict__ b2, const float* __restrict__ b3,
                        const float* __restrict__ b4,
                        float* __restrict__ ab)
{
    int tid = threadIdx.x;
    int i = tid >> 4, j = tid & 15;           // 160 threads: 16 lanes per output
    if (i < 10) {
        float sm = 0.f, sq = 0.f;
        for (int rep = j; rep < 64; rep += 16) {
            sm += statR2[rep * 32 + i];
            sq += statR2[rep * 32 + 16 + i];
        }
#pragma unroll
        for (int o = 8; o > 0; o >>= 1) {
            sm += __shfl_down(sm, o, 16);
            sq += __shfl_down(sq, o, 16);
        }
        if (j == 0) {
            int kb = i >> 1, c = i & 1;
            const float Nv[5] = {262144.f, 524288.f, 1572864.f, 2097152.f, 4194304.f};
            const float* gp[5] = {g0, g1, g2, g3, g4};
            const float* bp[5] = {b0, b1, b2, b3, b4};
            float mean = sm / Nv[kb];
            float var  = sq / Nv[kb] - mean * mean;
            float a = gp[kb][c] * rsqrtf(var + EPSV);
            ab[i * 2]     = a;
            ab[i * 2 + 1] = bp[kb][c] - mean * a;
        }
    }
}

// ---------------- BN+ReLU epilogue: bf16 z -> fp32 out (16 elems / thread) ----------------
// Two 16B z-loads issued together (2 in flight), 4x16B stores; grid halved.
__global__ __launch_bounds__(256) void k_bn_out(
    const unsigned short* __restrict__ z, const float* __restrict__ ab,
    float* __restrict__ out)
{
    int i16 = blockIdx.x * 256 + threadIdx.x;
    if (i16 >= 1081344) return;
    int kb, off16, cs16;
    if (i16 < 32768)       { kb = 0; off16 = 0;      cs16 = 2048;  }
    else if (i16 < 98304)  { kb = 1; off16 = 32768;  cs16 = 4096;  }
    else if (i16 < 294912) { kb = 2; off16 = 98304;  cs16 = 12288; }
    else if (i16 < 557056) { kb = 3; off16 = 294912; cs16 = 16384; }
    else                   { kb = 4; off16 = 557056; cs16 = 32768; }
    int c = ((i16 - off16) / cs16) & 1;
    float a = ab[(kb * 2 + c) * 2], b = ab[(kb * 2 + c) * 2 + 1];

    const unsigned short* zp = z + (size_t)i16 * 16;
    u32x4 w0 = *(const u32x4*)zp;          // 8 bf16
    u32x4 w1 = *(const u32x4*)(zp + 8);    // 8 bf16
    float* op = out + (size_t)i16 * 16;
#pragma unroll
    for (int h = 0; h < 2; ++h) {
        u32x4 w = h ? w1 : w0;
        float4 oA, oB;
        oA.x = fmaxf(fmaf(bf2f((unsigned short)(w[0] & 0xffffu)), a, b), 0.f);
        oA.y = fmaxf(fmaf(bf2f((unsigned short)(w[0] >> 16)),     a, b), 0.f);
        oA.z = fmaxf(fmaf(bf2f((unsigned short)(w[1] & 0xffffu)), a, b), 0.f);
        oA.w = fmaxf(fmaf(bf2f((unsigned short)(w[1] >> 16)),     a, b), 0.f);
        oB.x = fmaxf(fmaf(bf2f((unsigned short)(w[2] & 0xffffu)), a, b), 0.f);
        oB.y = fmaxf(fmaf(bf2f((unsigned short)(w[2] >> 16)),     a, b), 0.f);
        oB.z = fmaxf(fmaf(bf2f((unsigned short)(w[3] & 0xffffu)), a, b), 0.f);
        oB.w = fmaxf(fmaf(bf2f((unsigned short)(w[3] >> 16)),     a, b), 0.f);
        *(float4*)(op + h * 8)     = oA;
        *(float4*)(op + h * 8 + 4) = oB;
    }
}

// ---------------- launch ----------------
extern "C" void kernel_launch(void* const* d_in, const int* in_sizes, int n_in,
                              void* d_out, int out_size, void* d_ws, size_t ws_size,
                              hipStream_t stream)
{
    const float* x      = (const float*)d_in[0];
    const float* imean  = (const float*)d_in[1];
    const float* iscale = (const float*)d_in[2];
    const float* Wdeo   = (const float*)d_in[3];
    const float* gdeo   = (const float*)d_in[4];
    const float* bdeo   = (const float*)d_in[5];
    const float* Wdi[5] = {(const float*)d_in[7],  (const float*)d_in[10],
                           (const float*)d_in[13], (const float*)d_in[16],
                           (const float*)d_in[19]};
    const float* gdi[5] = {(const float*)d_in[8],  (const float*)d_in[11],
                           (const float*)d_in[14], (const float*)d_in[17],
                           (const float*)d_in[20]};
    const float* bdi[5] = {(const float*)d_in[9],  (const float*)d_in[12],
                           (const float*)d_in[15], (const float*)d_in[18],
                           (const float*)d_in[21]};
    float* out = (float*)d_out;
    float* ws  = (float*)d_ws;

    unsigned short* y  = (unsigned short*)(ws + YOFF);
    unsigned short* z  = (unsigned short*)(ws + ZOFF);
    unsigned short* w1 = (unsigned short*)(ws + W1OFF);
    unsigned short* w2 = (unsigned short*)(ws + W2OFF);
    float* st     = ws + STATF;
    float* da     = st + OFF_DA;
    float* db     = st + OFF_DB;
    float* diab   = st + OFF_DIAB;
    float* statR  = st + OFF_STATR;
    float* statR2 = st + OFF_STATR2;

    k_prep<<<348, 256, 0, stream>>>(Wdeo, Wdi[0], Wdi[1], Wdi[2], Wdi[3], Wdi[4],
                                    w1, w2, st);

    k_deoverlap<<<BB * CC * FF, 256, 0, stream>>>(x, imean, iscale, w1, y, statR);
    k_deo_ab<<<1, 512, 0, stream>>>(statR, gdeo, bdeo, da, db);

    k_deinterp_all<<<2560, 256, 0, stream>>>(y, w2, da, db, z, statR2);

    k_di_ab<<<1, 160, 0, stream>>>(statR2,
                                   gdi[0], gdi[1], gdi[2], gdi[3], gdi[4],
                                   bdi[0], bdi[1], bdi[2], bdi[3], bdi[4], diab);

    k_bn_out<<<4224, 256, 0, stream>>>(z, diab, out);
}

// Round 13
// 230.840 us; speedup vs baseline: 1.0347x; 1.0305x over previous
//
#include <hip/hip_runtime.h>
#include <hip/hip_bf16.h>
#include <cstddef>

// ---------------- problem constants ----------------
#define BB   8
#define CC   2
#define FF   256
#define TT   4160      // ncoefs
#define SS   64        // nb_slices
#define NW   128       // NWIN
#define KW   256       // 2*NWIN
#define EPSV 1e-5f

typedef __attribute__((ext_vector_type(8))) short bf16x8;   // 8 bf16 = 4 VGPRs
typedef __attribute__((ext_vector_type(4))) float f32x4;
typedef __attribute__((ext_vector_type(4))) unsigned int u32x4;

// ---------------- ws layout (float offsets) ----------------
#define YOFF    0
#define ZOFF    16777216
#define W1OFF   25427968
#define W2OFF   25444352
#define STATF   25462784
#define OFF_DA     256
#define OFF_DB     384
#define OFF_DIAB   544
#define OFF_STATR  1024    // 64 reps x [sum(128) | sq(128)]  (stage-1)
#define OFF_STATR2 17408   // 64 reps x [sum(16)  | sq(16) ]  (stage-2)
#define STAT_NZ 19456

// manual bf16 conversions (RNE) — cold paths only
__device__ __forceinline__ unsigned short f2bf(float f) {
    unsigned int u = __builtin_bit_cast(unsigned int, f);
    u = (u + 0x7FFFu + ((u >> 16) & 1u)) >> 16;
    return (unsigned short)u;
}
__device__ __forceinline__ float bf2f(unsigned short h) {
    return __builtin_bit_cast(float, (unsigned int)h << 16);
}
// packed f32x2 -> bf16x2 (RNE) via header intrinsic (lowers to v_cvt_pk_bf16_f32)
__device__ __forceinline__ unsigned int pk2bf(float lo, float hi) {
    float2 f; f.x = lo; f.y = hi;
    __hip_bfloat162 h = __float22bfloat162_rn(f);
    unsigned int r;
    __builtin_memcpy(&r, &h, 4);
    return r;
}

// ---------------- prep: zero stats + frag-ordered bf16 W_deo (w1) + W_di (w2) ----------------
__global__ __launch_bounds__(256) void k_prep(
    const float* __restrict__ Wdeo,
    const float* __restrict__ Wdi0, const float* __restrict__ Wdi1,
    const float* __restrict__ Wdi2, const float* __restrict__ Wdi3,
    const float* __restrict__ Wdi4,
    unsigned short* __restrict__ w1, unsigned short* __restrict__ w2,
    float* __restrict__ statz)
{
    int gid = blockIdx.x * 256 + threadIdx.x;
    if (gid < STAT_NZ) statz[gid] = 0.f;
    int id = gid - STAT_NZ;
    if (id >= 0 && id < 32768) {
        int j = id & 7, lane = (id >> 3) & 63, nt = (id >> 9) & 7, ks = id >> 12;
        int n = nt * 16 + (lane & 15);
        int k = ks * 32 + ((lane >> 4) << 3) + j;
        w1[id] = f2bf(Wdeo[n * KW + k]);
    }
    id -= 32768;
    if (id >= 0 && id < 36864) {
        const float* W; int base, Tk;
        if (id < 2048)       { W = Wdi0; base = 0;     Tk = 1; }
        else if (id < 6144)  { W = Wdi1; base = 2048;  Tk = 2; }
        else if (id < 12288) { W = Wdi2; base = 6144;  Tk = 3; }
        else if (id < 20480) { W = Wdi3; base = 12288; Tk = 4; }
        else                 { W = Wdi4; base = 20480; Tk = 8; }
        int e = id - base;
        int j = e & 7, lane = (e >> 3) & 63, rest = e >> 9;
        int t = rest % Tk, ks = rest / Tk;
        int n = t * 16 + (lane & 15);
        int k = ks * 32 + ((lane >> 4) << 3) + j;
        w2[id] = f2bf(W[n * NW + k]);
    }
}

// ---------------- stage 1: normalize + deoverlap MFMA + stats (1 row / block) ----------------
// STATIC 5-deep x load phase; zero pads (normalize-then-pad semantics).
// w1 B-fragments prefetched 2 ks ahead (ks=0,1 issued before the barrier):
// per-iteration MFMA+ds_read (~100-130 cyc) is shorter than the ~200 cyc L2
// latency of the next B-pair, so 1-deep prefetch left the wave stalling.
__global__ __launch_bounds__(256) void k_deoverlap(
    const float* __restrict__ x, const float* __restrict__ imean,
    const float* __restrict__ iscale, const unsigned short* __restrict__ w1,
    unsigned short* __restrict__ y, float* __restrict__ statR)
{
    __shared__ __align__(16) unsigned short xs[4288];
    __shared__ float psA[4][64], pqA[4][64];
    const int tid = threadIdx.x;
    const int r   = blockIdx.x;
    const int c   = (r >> 8) & 1;
    const int lane = tid & 63, wv = tid >> 6;
    const int q = lane >> 4, m = lane & 15;

    // ks=0 and ks=1 B-fragments: issue before staging (hide under vmcnt drain)
    bf16x8 Bc0 = *(const bf16x8*)(w1 + ((size_t)((2 * wv + 0) * 64 + lane) << 3));
    bf16x8 Bc1 = *(const bf16x8*)(w1 + ((size_t)((2 * wv + 1) * 64 + lane) << 3));
    bf16x8 Bn0 = *(const bf16x8*)(w1 + ((size_t)((8 + 2 * wv + 0) * 64 + lane) << 3));
    bf16x8 Bn1 = *(const bf16x8*)(w1 + ((size_t)((8 + 2 * wv + 1) * 64 + lane) << 3));

    {
        const float mval = imean[r & 255], sval = iscale[r & 255];
        const float* xr = x + (size_t)r * TT;
        // p4 = tid + k*256, k=0..4 (p4 < 1072). Valid x window: p4 in [16, 1056).
        float4 xv[5];
#pragma unroll
        for (int k = 0; k < 5; ++k) {
            int p4 = tid + k * 256;
            float4 v; v.x = 0.f; v.y = 0.f; v.z = 0.f; v.w = 0.f;
            if (p4 >= 16 && p4 < 1056)
                v = *(const float4*)&xr[p4 * 4 - 64];
            xv[k] = v;
        }
#pragma unroll
        for (int k = 0; k < 5; ++k) {
            int p4 = tid + k * 256;
            if (p4 < 1072) {
                int i = p4 * 4;
                int phys = i ^ (((i >> 6) & 7) << 3);   // 4-elem group contiguous under swizzle
                uint2 pk;
                if (p4 >= 16 && p4 < 1056) {
                    pk.x = pk2bf((xv[k].x + mval) * sval, (xv[k].y + mval) * sval);
                    pk.y = pk2bf((xv[k].z + mval) * sval, (xv[k].w + mval) * sval);
                } else {
                    pk.x = 0u; pk.y = 0u;               // zero-pad AFTER normalize semantics
                }
                *(uint2*)&xs[phys] = pk;
            }
        }
    }
    __syncthreads();

    f32x4 acc[4][2] = {};   // [stile][ntile]; D reg dim = n (contiguous in y)
#pragma unroll
    for (int ks = 0; ks < 8; ++ks) {
        bf16x8 Bm0, Bm1;
        if (ks < 6) {
            Bm0 = *(const bf16x8*)(w1 + ((size_t)(((ks + 2) * 8 + 2 * wv + 0) * 64 + lane) << 3));
            Bm1 = *(const bf16x8*)(w1 + ((size_t)(((ks + 2) * 8 + 2 * wv + 1) * 64 + lane) << 3));
        }
        const int k0 = ks * 32;
#pragma unroll
        for (int st = 0; st < 4; ++st) {
            int idx  = (st * 16 + m) * 64 + k0 + q * 8;
            int phys = idx ^ (((idx >> 6) & 7) << 3);
            bf16x8 A = *(const bf16x8*)&xs[phys];
            acc[st][0] = __builtin_amdgcn_mfma_f32_16x16x32_bf16(Bc0, A, acc[st][0], 0, 0, 0);
            acc[st][1] = __builtin_amdgcn_mfma_f32_16x16x32_bf16(Bc1, A, acc[st][1], 0, 0, 0);
        }
        Bc0 = Bn0; Bc1 = Bn1;
        Bn0 = Bm0; Bn1 = Bm1;
    }

    // y store: row s = st*16+m, cols n = (2wv+t)*16 + q*4 + reg -> one 8B store
#pragma unroll
    for (int st = 0; st < 4; ++st) {
        float ps = 0.f, pq = 0.f;
#pragma unroll
        for (int t = 0; t < 2; ++t) {
            uint2 u;
            u.x = pk2bf(acc[st][t][0], acc[st][t][1]);
            u.y = pk2bf(acc[st][t][2], acc[st][t][3]);
            *(uint2*)&y[(size_t)r * 8192 + (st * 16 + m) * NW + (2 * wv + t) * 16 + q * 4] = u;
#pragma unroll
            for (int reg = 0; reg < 4; ++reg) {
                float v = acc[st][t][reg];
                ps += v; pq += v * v;
            }
        }
        ps += __shfl_xor(ps, 16, 64);  pq += __shfl_xor(pq, 16, 64);
        ps += __shfl_xor(ps, 32, 64);  pq += __shfl_xor(pq, 32, 64);
        if (q == 0) { psA[wv][st * 16 + m] = ps; pqA[wv][st * 16 + m] = pq; }
    }
    __syncthreads();
    if (tid < 128) {
        int s = tid & 63, which = tid >> 6;
        float v = which ? (pqA[0][s] + pqA[1][s] + pqA[2][s] + pqA[3][s])
                        : (psA[0][s] + psA[1][s] + psA[2][s] + psA[3][s]);
        int rep = blockIdx.x & 63;
        atomicAdd(&statR[rep * 256 + which * 128 + c * SS + s], v);
    }
}

// ---------------- stage 1b: fold replicas -> per-(c,s) BN coefficients ----------------
__global__ void k_deo_ab(const float* __restrict__ statR,
                         const float* __restrict__ g, const float* __restrict__ be,
                         float* __restrict__ da, float* __restrict__ db)
{
    __shared__ float red[4][256];
    int tid = threadIdx.x;
    int i = tid & 127, h = tid >> 7;          // 512 threads: 4 rep-chunks
    float sm = 0.f, sq = 0.f;
    for (int rep = h; rep < 64; rep += 4) {
        sm += statR[rep * 256 + i];
        sq += statR[rep * 256 + 128 + i];
    }
    red[h][i] = sm; red[h][128 + i] = sq;
    __syncthreads();
    if (h == 0) {
        sm = red[0][i] + red[1][i] + red[2][i] + red[3][i];
        sq = red[0][128 + i] + red[1][128 + i] + red[2][128 + i] + red[3][128 + i];
        int c = i >> 6;
        const float N = (float)(BB * FF * NW);
        float mean = sm / N;
        float var  = sq / N - mean * mean;
        float a = g[c] * rsqrtf(var + EPSV);
        da[i] = a;
        db[i] = be[c] - mean * a;
    }
}

// ---------------- stage 2 body: fused BN+ReLU + GEMM for one bucket sub-block ----------------
// r10 interleaved form (one ar live at a time, low VGPR).
template <int Tk, int G>
__device__ __forceinline__ void deinterp_body(
    int sub,
    const unsigned short* __restrict__ y, const unsigned short* __restrict__ wb,
    const float* __restrict__ da, const float* __restrict__ db,
    unsigned short* __restrict__ zz, float* __restrict__ statR2,
    int p, int freqs, int kidx, float* ssum, float* ssq)
{
    constexpr int MT = Tk * 16;
    const int tid = threadIdx.x, lane = tid & 63, wv = tid >> 6;
    const int q = lane >> 4, m = lane & 15;
    const int bc = sub & 15;
    const int fg = sub >> 4;
    const int c  = bc & 1;
    const int s  = wv * 16 + m;
    const float aS = da[c * SS + s], bS = db[c * SS + s];

    f32x4 acc[G][Tk] = {};
    const unsigned short* ybase = y + ((size_t)(bc * FF + p + fg * G) * SS) * NW;

#pragma unroll
    for (int ks = 0; ks < 4; ++ks) {
        bf16x8 B[Tk];
#pragma unroll
        for (int t = 0; t < Tk; ++t)
            B[t] = *(const bf16x8*)(wb + ((size_t)((ks * Tk + t) * 64 + lane) << 3));
#pragma unroll
        for (int g = 0; g < G; ++g) {
            bf16x8 ar = *(const bf16x8*)(ybase + ((size_t)g * SS + s) * NW + ks * 32 + q * 8);
            u32x4 tp;
#pragma unroll
            for (int jj = 0; jj < 4; ++jj) {
                float f0 = fmaxf(fmaf(bf2f((unsigned short)ar[2 * jj]),     aS, bS), 0.f);
                float f1 = fmaxf(fmaf(bf2f((unsigned short)ar[2 * jj + 1]), aS, bS), 0.f);
                tp[jj] = pk2bf(f0, f1);
            }
            bf16x8 af;
            __builtin_memcpy(&af, &tp, 16);
#pragma unroll
            for (int t = 0; t < Tk; ++t)
                acc[g][t] = __builtin_amdgcn_mfma_f32_16x16x32_bf16(B[t], af, acc[g][t], 0, 0, 0);
        }
    }

    float ls = 0.f, lq = 0.f;
#pragma unroll
    for (int g = 0; g < G; ++g) {
        size_t zrow = ((size_t)(bc * freqs + fg * G + g) * SS + wv * 16 + m) * MT;
#pragma unroll
        for (int t = 0; t < Tk; ++t) {
            uint2 u;
            u.x = pk2bf(acc[g][t][0], acc[g][t][1]);
            u.y = pk2bf(acc[g][t][2], acc[g][t][3]);
            *(uint2*)&zz[zrow + t * 16 + q * 4] = u;
#pragma unroll
            for (int reg = 0; reg < 4; ++reg) {
                float v = acc[g][t][reg];
                ls += v; lq += v * v;
            }
        }
    }
#pragma unroll
    for (int o = 32; o > 0; o >>= 1) {
        ls += __shfl_down(ls, o, 64);
        lq += __shfl_down(lq, o, 64);
    }
    if (lane == 0) { ssum[wv] = ls; ssq[wv] = lq; }
    __syncthreads();
    if (tid == 0) {
        int rep = sub & 63;
        atomicAdd(&statR2[rep * 32 + kidx * 2 + c],      ssum[0] + ssum[1] + ssum[2] + ssum[3]);
        atomicAdd(&statR2[rep * 32 + 16 + kidx * 2 + c], ssq[0] + ssq[1] + ssq[2] + ssq[3]);
    }
}

// ---------------- stage 2 fused: all 5 buckets in one launch (G halved for 2x TLP) ----------------
//   [    0,  512) -> bucket3 Tk=4 G=2  (512 blocks)
//   [  512, 1024) -> bucket2 Tk=3 G=2  (512 blocks)
//   [ 1024, 2048) -> bucket4 Tk=8 G=1  (1024 blocks)
//   [ 2048, 2304) -> bucket1 Tk=2 G=2  (256 blocks)
//   [ 2304, 2560) -> bucket0 Tk=1 G=2  (256 blocks)
__global__ __launch_bounds__(256) void k_deinterp_all(
    const unsigned short* __restrict__ y, const unsigned short* __restrict__ w2,
    const float* __restrict__ da, const float* __restrict__ db,
    unsigned short* __restrict__ z, float* __restrict__ statR2)
{
    __shared__ float ssum[4], ssq[4];
    const int b = blockIdx.x;
    if (b < 512) {
        deinterp_body<4, 2>(b,        y, w2 + 12288, da, db, z + 4718592, statR2, 128, 64, 3, ssum, ssq);
    } else if (b < 1024) {
        deinterp_body<3, 2>(b - 512,  y, w2 + 6144,  da, db, z + 1572864, statR2,  64, 64, 2, ssum, ssq);
    } else if (b < 2048) {
        deinterp_body<8, 1>(b - 1024, y, w2 + 20480, da, db, z + 8912896, statR2, 192, 64, 4, ssum, ssq);
    } else if (b < 2304) {
        deinterp_body<2, 2>(b - 2048, y, w2 + 2048,  da, db, z + 524288,  statR2,  32, 32, 1, ssum, ssq);
    } else {
        deinterp_body<1, 2>(b - 2304, y, w2 + 0,     da, db, z + 0,       statR2,   0, 32, 0, ssum, ssq);
    }
}

// ---------------- stage 2b: fold replicas -> per-(bucket,c) BN coefficients ----------------
__global__ void k_di_ab(const float* __restrict__ statR2,
                        const float* __restrict__ g0, const float* __restrict__ g1,
                        const float* __restrict__ g2, const float* __restrict__ g3,
                        const float* __restrict__ g4,
                        const float* __restrict__ b0, const float* __restrict__ b1,
                        const float* __restrict__ b2, const float* __restrict__ b3,
                        const float* __restrict__ b4,
                        float* __restrict__ ab)
{
    int tid = threadIdx.x;
    int i = tid >> 4, j = tid & 15;           // 160 threads: 16 lanes per output
    if (i < 10) {
        float sm = 0.f, sq = 0.f;
        for (int rep = j; rep < 64; rep += 16) {
            sm += statR2[rep * 32 + i];
            sq += statR2[rep * 32 + 16 + i];
        }
#pragma unroll
        for (int o = 8; o > 0; o >>= 1) {
            sm += __shfl_down(sm, o, 16);
            sq += __shfl_down(sq, o, 16);
        }
        if (j == 0) {
            int kb = i >> 1, c = i & 1;
            const float Nv[5] = {262144.f, 524288.f, 1572864.f, 2097152.f, 4194304.f};
            const float* gp[5] = {g0, g1, g2, g3, g4};
            const float* bp[5] = {b0, b1, b2, b3, b4};
            float mean = sm / Nv[kb];
            float var  = sq / Nv[kb] - mean * mean;
            float a = gp[kb][c] * rsqrtf(var + EPSV);
            ab[i * 2]     = a;
            ab[i * 2 + 1] = bp[kb][c] - mean * a;
        }
    }
}

// ---------------- BN+ReLU epilogue: bf16 z -> fp32 out (8 elems / thread, strided) ----------------
// Thread t handles float4-units blk*512+t and blk*512+256+t: every load/store
// instruction is perfectly lane-contiguous (r12's contiguous-16 layout had
// 64B lane stride = 25% line coverage per instr -> 6us regression). All
// (kb,c) region boundaries are multiples of 256 float4-units, so each
// 256-unit sub-chunk is uniform. 8448*512 = 4325376 exactly (no tail).
__device__ __forceinline__ void bn_class(int i4, const float* __restrict__ ab,
                                         float& a, float& b)
{
    int kb, off4, cs4;
    if (i4 < 131072)       { kb = 0; off4 = 0;       cs4 = 8192;   }
    else if (i4 < 393216)  { kb = 1; off4 = 131072;  cs4 = 16384;  }
    else if (i4 < 1179648) { kb = 2; off4 = 393216;  cs4 = 49152;  }
    else if (i4 < 2228224) { kb = 3; off4 = 1179648; cs4 = 65536;  }
    else                   { kb = 4; off4 = 2228224; cs4 = 131072; }
    int c = ((i4 - off4) / cs4) & 1;
    a = ab[(kb * 2 + c) * 2];
    b = ab[(kb * 2 + c) * 2 + 1];
}

__global__ __launch_bounds__(256) void k_bn_out(
    const unsigned short* __restrict__ z, const float* __restrict__ ab,
    float* __restrict__ out)
{
    int i4a = blockIdx.x * 512 + threadIdx.x;
    int i4b = i4a + 256;

    // both loads issued back-to-back (2 in flight), fully coalesced
    ushort4 ua = *(const ushort4*)(z + (size_t)i4a * 4);
    ushort4 ub = *(const ushort4*)(z + (size_t)i4b * 4);

    float aA, bA, aB, bB;
    bn_class(i4a, ab, aA, bA);
    bn_class(i4b, ab, aB, bB);

    float4 oa, ob;
    oa.x = fmaxf(fmaf(bf2f(ua.x), aA, bA), 0.f);
    oa.y = fmaxf(fmaf(bf2f(ua.y), aA, bA), 0.f);
    oa.z = fmaxf(fmaf(bf2f(ua.z), aA, bA), 0.f);
    oa.w = fmaxf(fmaf(bf2f(ua.w), aA, bA), 0.f);
    ob.x = fmaxf(fmaf(bf2f(ub.x), aB, bB), 0.f);
    ob.y = fmaxf(fmaf(bf2f(ub.y), aB, bB), 0.f);
    ob.z = fmaxf(fmaf(bf2f(ub.z), aB, bB), 0.f);
    ob.w = fmaxf(fmaf(bf2f(ub.w), aB, bB), 0.f);

    *(float4*)(out + (size_t)i4a * 4) = oa;
    *(float4*)(out + (size_t)i4b * 4) = ob;
}

// ---------------- launch ----------------
extern "C" void kernel_launch(void* const* d_in, const int* in_sizes, int n_in,
                              void* d_out, int out_size, void* d_ws, size_t ws_size,
                              hipStream_t stream)
{
    const float* x      = (const float*)d_in[0];
    const float* imean  = (const float*)d_in[1];
    const float* iscale = (const float*)d_in[2];
    const float* Wdeo   = (const float*)d_in[3];
    const float* gdeo   = (const float*)d_in[4];
    const float* bdeo   = (const float*)d_in[5];
    const float* Wdi[5] = {(const float*)d_in[7],  (const float*)d_in[10],
                           (const float*)d_in[13], (const float*)d_in[16],
                           (const float*)d_in[19]};
    const float* gdi[5] = {(const float*)d_in[8],  (const float*)d_in[11],
                           (const float*)d_in[14], (const float*)d_in[17],
                           (const float*)d_in[20]};
    const float* bdi[5] = {(const float*)d_in[9],  (const float*)d_in[12],
                           (const float*)d_in[15], (const float*)d_in[18],
                           (const float*)d_in[21]};
    float* out = (float*)d_out;
    float* ws  = (float*)d_ws;

    unsigned short* y  = (unsigned short*)(ws + YOFF);
    unsigned short* z  = (unsigned short*)(ws + ZOFF);
    unsigned short* w1 = (unsigned short*)(ws + W1OFF);
    unsigned short* w2 = (unsigned short*)(ws + W2OFF);
    float* st     = ws + STATF;
    float* da     = st + OFF_DA;
    float* db     = st + OFF_DB;
    float* diab   = st + OFF_DIAB;
    float* statR  = st + OFF_STATR;
    float* statR2 = st + OFF_STATR2;

    k_prep<<<348, 256, 0, stream>>>(Wdeo, Wdi[0], Wdi[1], Wdi[2], Wdi[3], Wdi[4],
                                    w1, w2, st);

    k_deoverlap<<<BB * CC * FF, 256, 0, stream>>>(x, imean, iscale, w1, y, statR);
    k_deo_ab<<<1, 512, 0, stream>>>(statR, gdeo, bdeo, da, db);

    k_deinterp_all<<<2560, 256, 0, stream>>>(y, w2, da, db, z, statR2);

    k_di_ab<<<1, 160, 0, stream>>>(statR2,
                                   gdi[0], gdi[1], gdi[2], gdi[3], gdi[4],
                                   bdi[0], bdi[1], bdi[2], bdi[3], bdi[4], diab);

    k_bn_out<<<8448, 256, 0, stream>>>(z, diab, out);
}